// Round 10
// baseline (429.634 us; speedup 1.0000x reference)
//
#include <hip/hip_runtime.h>
#include <hip/hip_bf16.h>

typedef __bf16 bf16_t;
typedef __bf16 bf16x4 __attribute__((ext_vector_type(4)));
typedef __bf16 bf16x8 __attribute__((ext_vector_type(8)));
typedef float f32x4 __attribute__((ext_vector_type(4)));

static __device__ __forceinline__ bf16x8 bzero8() {
  bf16x8 v;
#pragma unroll
  for (int j = 0; j < 8; j++) v[j] = (bf16_t)0.f;
  return v;
}

// async global->LDS, 16B per lane; LDS dest = wave-uniform base + lane*16
static __device__ __forceinline__ void async_copy16(const bf16_t* g, bf16_t* l) {
  __builtin_amdgcn_global_load_lds((const __attribute__((address_space(1))) void*)g,
                                   (__attribute__((address_space(3))) void*)l,
                                   16, 0, 0);
}
#define WAVE_LGKM() asm volatile("s_waitcnt lgkmcnt(0)" ::: "memory")

static __device__ __forceinline__ float fast_exp2(float x) {
  float r;
  asm volatile("v_exp_f32 %0, %1" : "=v"(r) : "v"(x));
  return r;
}

#define QK_SCALE 0.18033688f  /* 0.125 * log2(e) */
#define TOKC ((size_t)4608 * 512)

// ---------------- dtype probe ----------------
__global__ void probe_kernel(const void* x, int* flag) {
  if (threadIdx.x != 0 || blockIdx.x != 0) return;
  const unsigned short* u = (const unsigned short*)x;
  int insane = 0;
  for (int j = 0; j < 512; j++) {
    unsigned short h = u[j];
    int e = (h >> 7) & 0xFF;
    if (e == 0xFF || e > 140 || (e != 0 && e < 100)) insane++;
  }
  *flag = (insane > 16) ? 1 : 0;  // 1 => fp32 I/O
}

// ---------------- convert inputs to bf16 (vectorized x4) ----------------
struct ConvArgs { const void* src[28]; int n[28]; int off[28]; };
__global__ __launch_bounds__(256) void convert_kernel(ConvArgs a, const int* flag,
                                                      bf16_t* dst) {
  int i = blockIdx.y;
  if (i >= 28) return;
  int n = a.n[i];
  if (n == 0) return;
  const void* s = a.src[i];
  bf16_t* d = dst + a.off[i];
  bool f32 = (*flag != 0);
  int n4 = n >> 2;
  for (int j = blockIdx.x * 256 + threadIdx.x; j < n4; j += gridDim.x * 256) {
    bf16x4 o;
    if (f32) {
      float4 v = ((const float4*)s)[j];
      o[0] = (bf16_t)v.x; o[1] = (bf16_t)v.y; o[2] = (bf16_t)v.z; o[3] = (bf16_t)v.w;
    } else {
      o = ((const bf16x4*)s)[j];
    }
    ((bf16x4*)d)[j] = o;
  }
  int base = n4 << 2;
  int j = base + blockIdx.x * 256 + threadIdx.x;
  if (j < n) {
    float v = f32 ? ((const float*)s)[j] : (float)((const bf16_t*)s)[j];
    d[j] = (bf16_t)v;
  }
}

// -------- batched weight transpose [K][N] -> [N][K], reads raw dtype --------
struct TransArgs { const void* src[10]; int dst_off[10]; int K[10]; int N[10]; };
__global__ __launch_bounds__(256) void transpose_kernel(TransArgs ta, const int* flag,
                                                        bf16_t* __restrict__ wt) {
  int wi = blockIdx.y;
  int K = ta.K[wi], N = ta.N[wi];
  int tiles_n = N >> 6;
  int tile = blockIdx.x;
  if (tile >= tiles_n * (K >> 6)) return;
  int tk = tile / tiles_n, tn = tile - tk * tiles_n;
  int k0 = tk * 64, n0 = tn * 64;
  bf16_t* dst = wt + ta.dst_off[wi];
  bool f32 = (*flag != 0);
  __shared__ bf16_t tl[64][66];
  int t = threadIdx.x;
  int r = t >> 2, c = (t & 3) * 16;
  if (f32) {
    const float* src = (const float*)ta.src[wi] + (size_t)(k0 + r) * N + n0 + c;
#pragma unroll
    for (int q = 0; q < 4; q++) {
      float4 v = *(const float4*)(src + q * 4);
      tl[r][c + q * 4 + 0] = (bf16_t)v.x;
      tl[r][c + q * 4 + 1] = (bf16_t)v.y;
      tl[r][c + q * 4 + 2] = (bf16_t)v.z;
      tl[r][c + q * 4 + 3] = (bf16_t)v.w;
    }
  } else {
    const bf16_t* src = (const bf16_t*)ta.src[wi] + (size_t)(k0 + r) * N + n0 + c;
    bf16x8 v0 = *(const bf16x8*)(src);
    bf16x8 v1 = *(const bf16x8*)(src + 8);
#pragma unroll
    for (int j = 0; j < 8; j++) { tl[r][c + j] = v0[j]; tl[r][c + 8 + j] = v1[j]; }
  }
  __syncthreads();
  bf16x8 o0, o1;
#pragma unroll
  for (int j = 0; j < 8; j++) { o0[j] = tl[c + j][r]; o1[j] = tl[c + 8 + j][r]; }
  *(bf16x8*)(dst + (size_t)(n0 + r) * K + k0 + c) = o0;
  *(bf16x8*)(dst + (size_t)(n0 + r) * K + k0 + c + 8) = o1;
}

// ---------------- GroupNorm stats ----------------
__global__ __launch_bounds__(256) void gn_stats_kernel(const bf16_t* __restrict__ x,
                                                       float* __restrict__ stats) {
  const bf16x8* base = (const bf16x8*)(x + (size_t)blockIdx.x * 36864);
  float s = 0.f, ss = 0.f;
  for (int i = threadIdx.x; i < 4608; i += 256) {
    bf16x8 v = base[i];
#pragma unroll
    for (int j = 0; j < 8; j++) { float f = (float)v[j]; s += f; ss += f * f; }
  }
  __shared__ float red[8];
#pragma unroll
  for (int off = 32; off > 0; off >>= 1) { s += __shfl_down(s, off); ss += __shfl_down(ss, off); }
  int wid = threadIdx.x >> 6;
  if ((threadIdx.x & 63) == 0) { red[wid] = s; red[4 + wid] = ss; }
  __syncthreads();
  if (threadIdx.x == 0) {
    float S = red[0] + red[1] + red[2] + red[3];
    float SS = red[4] + red[5] + red[6] + red[7];
    const float inv = 1.0f / 36864.0f;
    float mean = S * inv;
    float var = SS * inv - mean * mean;
    stats[blockIdx.x * 2] = mean;
    stats[blockIdx.x * 2 + 1] = rsqrtf(fmaxf(var, 0.f) + 1e-6f);
  }
}

// GN normalize + tiled transpose [B,C,HW] -> xnt[(b*2304+p)][c]
__global__ __launch_bounds__(256) void gn_apply_kernel(const bf16_t* __restrict__ x,
                                                       const float* __restrict__ stats,
                                                       const bf16_t* __restrict__ g,
                                                       const bf16_t* __restrict__ bb,
                                                       bf16_t* __restrict__ xnt) {
  int p0 = blockIdx.x * 64, c0 = blockIdx.y * 64, bz = blockIdx.z;
  __shared__ bf16_t tl[64][66];
  int t = threadIdx.x;
  int r = t >> 2, cc = (t & 3) * 16;
  int c = c0 + r;
  float mean = stats[(bz * 32 + (c >> 4)) * 2];
  float rstd = stats[(bz * 32 + (c >> 4)) * 2 + 1];
  float gg = (float)g[c], bbv = (float)bb[c];
  const bf16_t* row = x + ((size_t)(bz * 512 + c)) * 2304 + p0 + cc;
  bf16x8 v0 = *(const bf16x8*)(row);
  bf16x8 v1 = *(const bf16x8*)(row + 8);
#pragma unroll
  for (int j = 0; j < 8; j++) {
    tl[r][cc + j] = (bf16_t)(((float)v0[j] - mean) * rstd * gg + bbv);
    tl[r][cc + 8 + j] = (bf16_t)(((float)v1[j] - mean) * rstd * gg + bbv);
  }
  __syncthreads();
  bf16x8 o0, o1;
#pragma unroll
  for (int j = 0; j < 8; j++) { o0[j] = tl[cc + j][r]; o1[j] = tl[cc + 8 + j][r]; }
  bf16_t* orow = xnt + ((size_t)(bz * 2304 + p0 + r)) * 512 + c0 + cc;
  *(bf16x8*)(orow) = o0;
  *(bf16x8*)(orow + 8) = o1;
}

// ---------------- LayerNorm ----------------
__global__ __launch_bounds__(256) void ln_kernel(const float* __restrict__ in,
                                                 const bf16_t* __restrict__ g,
                                                 const bf16_t* __restrict__ b,
                                                 bf16_t* __restrict__ out) {
  int tok = blockIdx.x * 4 + (threadIdx.x >> 6);
  int lane = threadIdx.x & 63;
  const float* row = in + (size_t)tok * 512 + lane * 8;
  float f[8];
  float s = 0.f, ss = 0.f;
#pragma unroll
  for (int j = 0; j < 8; j++) { f[j] = row[j]; s += f[j]; ss += f[j] * f[j]; }
#pragma unroll
  for (int off = 32; off > 0; off >>= 1) { s += __shfl_xor(s, off); ss += __shfl_xor(ss, off); }
  float mean = s * (1.0f / 512.0f);
  float var = ss * (1.0f / 512.0f) - mean * mean;
  float rstd = rsqrtf(fmaxf(var, 0.f) + 1e-5f);
  bf16x8 gv = *(const bf16x8*)(g + lane * 8);
  bf16x8 bv = *(const bf16x8*)(b + lane * 8);
  bf16x8 o;
#pragma unroll
  for (int j = 0; j < 8; j++) o[j] = (bf16_t)((f[j] - mean) * rstd * (float)gv[j] + (float)bv[j]);
  *(bf16x8*)(out + (size_t)tok * 512 + lane * 8) = o;
}

// ============ 64x64 dbuf GEMM, BK=64, 32x32 wave-tiles (proven) ======
template <int SMODE, int MODE>
__global__ __launch_bounds__(256) void gemm64d_kernel(
    const bf16_t* __restrict__ A, int lda,
    const bf16_t* __restrict__ Bt, int K, int N,
    const bf16_t* __restrict__ bias, float oscale,
    float* __restrict__ t32, bf16_t* __restrict__ C,
    const bf16_t* __restrict__ resb, const float* __restrict__ resf,
    float* __restrict__ Cf, const int* dflag) {
  __shared__ bf16_t As[2][4096];
  __shared__ bf16_t Bs[2][4096];
  int t = threadIdx.x, w = t >> 6, quad = (t >> 4) & 3, l16 = t & 15;
  int m0 = blockIdx.y * 64, n0 = blockIdx.x * 64;
  int wm = (w >> 1) * 32, wn = (w & 1) * 32;
  const f32x4 z4 = {0.f, 0.f, 0.f, 0.f};
  f32x4 acc[2][2] = {{z4, z4}, {z4, z4}};
  int r0 = t >> 3, c0 = ((t & 7) ^ (r0 & 7)) * 8;
  int r1 = r0 + 32, c1 = ((t & 7) ^ (r1 & 7)) * 8;
  const bf16_t* Ar0 = A + (size_t)(m0 + r0) * lda + c0;
  const bf16_t* Ar1 = A + (size_t)(m0 + r1) * lda + c1;
  const bf16_t* Br0 = Bt + (size_t)(n0 + r0) * K + c0;
  const bf16_t* Br1 = Bt + (size_t)(n0 + r1) * K + c1;
  int niter = K >> 6;
  async_copy16(Ar0, As[0] + w * 512);
  async_copy16(Ar1, As[0] + 2048 + w * 512);
  async_copy16(Br0, Bs[0] + w * 512);
  async_copy16(Br1, Bs[0] + 2048 + w * 512);
  for (int it = 0; it < niter; it++) {
    __syncthreads();
    if (it + 1 < niter) {
      int k0 = (it + 1) << 6;
      int nb = (it + 1) & 1;
      async_copy16(Ar0 + k0, As[nb] + w * 512);
      async_copy16(Ar1 + k0, As[nb] + 2048 + w * 512);
      async_copy16(Br0 + k0, Bs[nb] + w * 512);
      async_copy16(Br1 + k0, Bs[nb] + 2048 + w * 512);
    }
    int cb = it & 1;
    bf16x8 af[2][2], bff[2][2];
#pragma unroll
    for (int mi = 0; mi < 2; mi++) {
      int rr = wm + mi * 16 + l16;
      af[mi][0] = *(const bf16x8*)&As[cb][(rr * 8 + (quad ^ (rr & 7))) * 8];
      af[mi][1] = *(const bf16x8*)&As[cb][(rr * 8 + ((quad + 4) ^ (rr & 7))) * 8];
    }
#pragma unroll
    for (int ni = 0; ni < 2; ni++) {
      int rr = wn + ni * 16 + l16;
      bff[ni][0] = *(const bf16x8*)&Bs[cb][(rr * 8 + (quad ^ (rr & 7))) * 8];
      bff[ni][1] = *(const bf16x8*)&Bs[cb][(rr * 8 + ((quad + 4) ^ (rr & 7))) * 8];
    }
#pragma unroll
    for (int mi = 0; mi < 2; mi++)
#pragma unroll
      for (int ni = 0; ni < 2; ni++) {
        acc[mi][ni] = __builtin_amdgcn_mfma_f32_16x16x32_bf16(af[mi][0], bff[ni][0], acc[mi][ni], 0, 0, 0);
        acc[mi][ni] = __builtin_amdgcn_mfma_f32_16x16x32_bf16(af[mi][1], bff[ni][1], acc[mi][ni], 0, 0, 0);
      }
  }
  const bool f32m = (MODE == 3) && (*dflag != 0);
#pragma unroll
  for (int mi = 0; mi < 2; mi++)
#pragma unroll
    for (int ni = 0; ni < 2; ni++) {
      int col = n0 + wn + ni * 16 + l16;
      float bv = bias ? (float)bias[col] : 0.f;
#pragma unroll
      for (int r = 0; r < 4; r++) {
        int row = m0 + wm + mi * 16 + quad * 4 + r;
        float v = acc[mi][ni][r] + bv;
        size_t addr;
        if (SMODE == 0) {
          addr = (size_t)row * N + col;
        } else {
          int b2 = row / 2304; int p = row - b2 * 2304;
          addr = ((size_t)(b2 * 512 + col)) * 2304 + p;
        }
        if (MODE == 0) C[addr] = (bf16_t)(v * oscale);
        else if (MODE == 1) { t32[addr] = v; C[addr] = (bf16_t)v; }
        else if (MODE == 2) { v += t32[addr]; t32[addr] = v; C[addr] = (bf16_t)v; }
        else {
          v += f32m ? resf[addr] : (float)resb[addr];
          if (f32m) Cf[addr] = v; else C[addr] = (bf16_t)v;
        }
      }
    }
}

// ---- fused QKV3: ONE dispatch, A staged once, 3 B tiles, 3 outputs ----
__global__ __launch_bounds__(256) void qkv3_kernel(
    const bf16_t* __restrict__ A,
    const bf16_t* __restrict__ BtQ, const bf16_t* __restrict__ BtK,
    const bf16_t* __restrict__ BtV,
    bf16_t* __restrict__ Qo, bf16_t* __restrict__ Ko, bf16_t* __restrict__ Vt) {
  __shared__ bf16_t As[2][4096];
  __shared__ bf16_t Bs[3][2][4096];
  int t = threadIdx.x, w = t >> 6, quad = (t >> 4) & 3, l16 = t & 15;
  int m0 = blockIdx.y * 64, n0 = blockIdx.x * 64;
  int wm = (w >> 1) * 32, wn = (w & 1) * 32;
  const f32x4 z4 = {0.f, 0.f, 0.f, 0.f};
  f32x4 acc[3][2][2];
#pragma unroll
  for (int z = 0; z < 3; z++)
#pragma unroll
    for (int mi = 0; mi < 2; mi++)
#pragma unroll
      for (int ni = 0; ni < 2; ni++) acc[z][mi][ni] = z4;
  int r0 = t >> 3, c0 = ((t & 7) ^ (r0 & 7)) * 8;
  int r1 = r0 + 32, c1 = ((t & 7) ^ (r1 & 7)) * 8;
  const bf16_t* Ar0 = A + (size_t)(m0 + r0) * 512 + c0;
  const bf16_t* Ar1 = A + (size_t)(m0 + r1) * 512 + c1;
  const bf16_t* Bw[3] = {BtQ, BtK, BtV};
  const bf16_t* Br0[3];
  const bf16_t* Br1[3];
#pragma unroll
  for (int z = 0; z < 3; z++) {
    Br0[z] = Bw[z] + (size_t)(n0 + r0) * 512 + c0;
    Br1[z] = Bw[z] + (size_t)(n0 + r1) * 512 + c1;
  }
  async_copy16(Ar0, As[0] + w * 512);
  async_copy16(Ar1, As[0] + 2048 + w * 512);
#pragma unroll
  for (int z = 0; z < 3; z++) {
    async_copy16(Br0[z], Bs[z][0] + w * 512);
    async_copy16(Br1[z], Bs[z][0] + 2048 + w * 512);
  }
  for (int it = 0; it < 8; it++) {
    __syncthreads();
    if (it + 1 < 8) {
      int k0 = (it + 1) << 6;
      int nb = (it + 1) & 1;
      async_copy16(Ar0 + k0, As[nb] + w * 512);
      async_copy16(Ar1 + k0, As[nb] + 2048 + w * 512);
#pragma unroll
      for (int z = 0; z < 3; z++) {
        async_copy16(Br0[z] + k0, Bs[z][nb] + w * 512);
        async_copy16(Br1[z] + k0, Bs[z][nb] + 2048 + w * 512);
      }
    }
    int cb = it & 1;
    bf16x8 af[2][2];
#pragma unroll
    for (int mi = 0; mi < 2; mi++) {
      int rr = wm + mi * 16 + l16;
      af[mi][0] = *(const bf16x8*)&As[cb][(rr * 8 + (quad ^ (rr & 7))) * 8];
      af[mi][1] = *(const bf16x8*)&As[cb][(rr * 8 + ((quad + 4) ^ (rr & 7))) * 8];
    }
#pragma unroll
    for (int z = 0; z < 3; z++) {
      bf16x8 bff[2][2];
#pragma unroll
      for (int ni = 0; ni < 2; ni++) {
        int rr = wn + ni * 16 + l16;
        bff[ni][0] = *(const bf16x8*)&Bs[z][cb][(rr * 8 + (quad ^ (rr & 7))) * 8];
        bff[ni][1] = *(const bf16x8*)&Bs[z][cb][(rr * 8 + ((quad + 4) ^ (rr & 7))) * 8];
      }
#pragma unroll
      for (int mi = 0; mi < 2; mi++)
#pragma unroll
        for (int ni = 0; ni < 2; ni++) {
          acc[z][mi][ni] = __builtin_amdgcn_mfma_f32_16x16x32_bf16(af[mi][0], bff[ni][0], acc[z][mi][ni], 0, 0, 0);
          acc[z][mi][ni] = __builtin_amdgcn_mfma_f32_16x16x32_bf16(af[mi][1], bff[ni][1], acc[z][mi][ni], 0, 0, 0);
        }
    }
  }
#pragma unroll
  for (int mi = 0; mi < 2; mi++)
#pragma unroll
    for (int ni = 0; ni < 2; ni++) {
      int col = n0 + wn + ni * 16 + l16;
#pragma unroll
      for (int r = 0; r < 4; r++) {
        int row = m0 + wm + mi * 16 + quad * 4 + r;
        Qo[(size_t)row * 512 + col] = (bf16_t)(acc[0][mi][ni][r] * QK_SCALE);
        Ko[(size_t)row * 512 + col] = (bf16_t)acc[1][mi][ni][r];
        int b2 = row / 2304; int p = row - b2 * 2304;
        Vt[((size_t)(b2 * 512 + col)) * 2304 + p] = (bf16_t)acc[2][mi][ni][r];
      }
    }
}

// ------- fused GEGLU ff1: 128x128 tile (a+g halves), BK=32 dbuf -------
// Granule g (8 elems): row=g>>2, kc=((g&3)^(row&3))*8. Frag(row,quad)=row*4+(quad^(row&3)).
__global__ __launch_bounds__(256) void ff1_kernel(const bf16_t* __restrict__ A,   // [4608,512]
                                                  const bf16_t* __restrict__ Bt,  // [4096,512]
                                                  const bf16_t* __restrict__ bias,
                                                  bf16_t* __restrict__ U) {       // [4608,2048]
  __shared__ bf16_t As[2][4096];
  __shared__ bf16_t Ba[2][4096];
  __shared__ bf16_t Bg[2][4096];
  int t = threadIdx.x, w = t >> 6, quad = (t >> 4) & 3, l16 = t & 15;
  int m0 = blockIdx.y * 128, n0 = blockIdx.x * 128;
  int wm = (w >> 1) * 64, wn = (w & 1) * 64;
  const f32x4 z4 = {0.f, 0.f, 0.f, 0.f};
  f32x4 aa[4][4], gg[4][4];
#pragma unroll
  for (int i = 0; i < 4; i++)
#pragma unroll
    for (int j = 0; j < 4; j++) { aa[i][j] = z4; gg[i][j] = z4; }
  int r0 = t >> 2, c0 = ((t & 3) ^ (r0 & 3)) * 8;
  int g1 = t + 256;
  int r1 = g1 >> 2, c1 = ((g1 & 3) ^ (r1 & 3)) * 8;
  const bf16_t* Ar0 = A + (size_t)(m0 + r0) * 512 + c0;
  const bf16_t* Ar1 = A + (size_t)(m0 + r1) * 512 + c1;
  const bf16_t* Ba0 = Bt + (size_t)(n0 + r0) * 512 + c0;
  const bf16_t* Ba1 = Bt + (size_t)(n0 + r1) * 512 + c1;
  const bf16_t* Bg0 = Bt + (size_t)(2048 + n0 + r0) * 512 + c0;
  const bf16_t* Bg1 = Bt + (size_t)(2048 + n0 + r1) * 512 + c1;
  async_copy16(Ar0, As[0] + w * 512);
  async_copy16(Ar1, As[0] + 2048 + w * 512);
  async_copy16(Ba0, Ba[0] + w * 512);
  async_copy16(Ba1, Ba[0] + 2048 + w * 512);
  async_copy16(Bg0, Bg[0] + w * 512);
  async_copy16(Bg1, Bg[0] + 2048 + w * 512);
  for (int it = 0; it < 16; it++) {
    __syncthreads();
    if (it + 1 < 16) {
      int k0 = (it + 1) << 5;
      int nb = (it + 1) & 1;
      async_copy16(Ar0 + k0, As[nb] + w * 512);
      async_copy16(Ar1 + k0, As[nb] + 2048 + w * 512);
      async_copy16(Ba0 + k0, Ba[nb] + w * 512);
      async_copy16(Ba1 + k0, Ba[nb] + 2048 + w * 512);
      async_copy16(Bg0 + k0, Bg[nb] + w * 512);
      async_copy16(Bg1 + k0, Bg[nb] + 2048 + w * 512);
    }
    int cb = it & 1;
    bf16x8 af[4], ba[4], bg[4];
#pragma unroll
    for (int mi = 0; mi < 4; mi++) {
      int rr = wm + mi * 16 + l16;
      af[mi] = *(const bf16x8*)&As[cb][(rr * 4 + (quad ^ (rr & 3))) * 8];
    }
#pragma unroll
    for (int ni = 0; ni < 4; ni++) {
      int rr = wn + ni * 16 + l16;
      int off = (rr * 4 + (quad ^ (rr & 3))) * 8;
      ba[ni] = *(const bf16x8*)&Ba[cb][off];
      bg[ni] = *(const bf16x8*)&Bg[cb][off];
    }
#pragma unroll
    for (int mi = 0; mi < 4; mi++)
#pragma unroll
      for (int ni = 0; ni < 4; ni++) {
        aa[mi][ni] = __builtin_amdgcn_mfma_f32_16x16x32_bf16(af[mi], ba[ni], aa[mi][ni], 0, 0, 0);
        gg[mi][ni] = __builtin_amdgcn_mfma_f32_16x16x32_bf16(af[mi], bg[ni], gg[mi][ni], 0, 0, 0);
      }
  }
#pragma unroll
  for (int mi = 0; mi < 4; mi++)
#pragma unroll
    for (int ni = 0; ni < 4; ni++) {
      int col = n0 + wn + ni * 16 + l16;
      float bba = (float)bias[col], bbg = (float)bias[col + 2048];
#pragma unroll
      for (int r = 0; r < 4; r++) {
        int row = m0 + wm + mi * 16 + quad * 4 + r;
        float a = aa[mi][ni][r] + bba;
        float g = gg[mi][ni][r] + bbg;
        float gl = 0.5f * g * (1.0f + erff(g * 0.70710678118654752f));
        U[(size_t)row * 2048 + col] = (bf16_t)(a * gl);
      }
    }
}

// -------- cross K/V merged (z=0: K->kbuf; z=1: V->vtb), M=154, K=768 --------
__global__ __launch_bounds__(256) void kv2_kernel(const bf16_t* __restrict__ A,
                                                  const bf16_t* __restrict__ Bk,
                                                  const bf16_t* __restrict__ Bv,
                                                  bf16_t* __restrict__ Ck,
                                                  bf16_t* __restrict__ Cv) {
  const int M = 154, N = 512, K = 768;
  int z = blockIdx.z;
  const bf16_t* B = z ? Bv : Bk;
  __shared__ alignas(16) bf16_t As[64][40];
  __shared__ alignas(16) bf16_t Bs[64][40];
  int t = threadIdx.x;
  int m0 = blockIdx.y * 64, n0 = blockIdx.x * 64;
  int w = t >> 6, lane = t & 63, quad = lane >> 4, l16 = lane & 15;
  int ar = t >> 2, ac = (t & 3) * 8;
  int br = t >> 3, bc = (t & 7) * 8;
  const f32x4 z4 = {0.f, 0.f, 0.f, 0.f};
  f32x4 acc[4] = {z4, z4, z4, z4};
  int gm = m0 + ar;
  const bool a_ok = gm < M;
  for (int k0 = 0; k0 < K; k0 += 32) {
    bf16x8 av = a_ok ? *(const bf16x8*)(A + (size_t)gm * K + k0 + ac) : bzero8();
    bf16x8 bv = *(const bf16x8*)(B + (size_t)(k0 + br) * N + n0 + bc);
    __syncthreads();
    *(bf16x8*)(&As[ar][ac]) = av;
#pragma unroll
    for (int j = 0; j < 8; j++) Bs[bc + j][br] = bv[j];
    __syncthreads();
    bf16x8 afrag = *(const bf16x8*)(&As[w * 16 + l16][quad * 8]);
#pragma unroll
    for (int kb = 0; kb < 4; kb++) {
      bf16x8 bfrag = *(const bf16x8*)(&Bs[kb * 16 + l16][quad * 8]);
      acc[kb] = __builtin_amdgcn_mfma_f32_16x16x32_bf16(afrag, bfrag, acc[kb], 0, 0, 0);
    }
  }
#pragma unroll
  for (int kb = 0; kb < 4; kb++) {
    int col = n0 + kb * 16 + l16;
#pragma unroll
    for (int r = 0; r < 4; r++) {
      int row = m0 + w * 16 + quad * 4 + r;
      if (row < M) {
        float v = acc[kb][r];
        if (z == 0) Ck[(size_t)row * N + col] = (bf16_t)v;
        else {
          int b2 = row / 77; int p = row - b2 * 77;
          Cv[((size_t)(b2 * 512 + col)) * 128 + p] = (bf16_t)v;
        }
      }
    }
  }
}

// ---- Flash v7: K-split (additive no-max softmax), 16 q/wave, dbuf staging ----
// KSPLIT>1: writes fp32 partial O (unnormalized) + partial l per split.
template <int KSPLIT, bool MASK>
__global__ __launch_bounds__(256) void flash7_kernel(const bf16_t* __restrict__ q,
                                                     const bf16_t* __restrict__ kk,
                                                     const bf16_t* __restrict__ vt,
                                                     bf16_t* __restrict__ out,
                                                     float* __restrict__ Of,
                                                     float* __restrict__ lp,
                                                     int n_k, int kv_bstride, int vt_len) {
  __shared__ bf16_t Ks[2][4096];
  __shared__ bf16_t Vs[2][4096];
  __shared__ bf16_t p_lds[4][16 * 72];
  int t = threadIdx.x, w = t >> 6, quad = (t >> 4) & 3, l16 = t & 15;
  int b = blockIdx.y >> 3, h = blockIdx.y & 7;
  int s = (KSPLIT > 1) ? blockIdx.z : 0;
  int chunk = n_k / KSPLIT;
  int q0 = blockIdx.x * 64 + w * 16;
  const bf16_t* qrow = q + ((size_t)(b * 2304 + q0 + l16)) * 512 + h * 64 + quad * 8;
  bf16x8 qa0 = *(const bf16x8*)(qrow);
  bf16x8 qa1 = *(const bf16x8*)(qrow + 32);
  const f32x4 z4 = {0.f, 0.f, 0.f, 0.f};
  f32x4 o[4] = {z4, z4, z4, z4};
  float l_i = 0.f;
  const bf16_t* kbase = kk + (size_t)b * kv_bstride + h * 64 + (size_t)s * chunk * 512;
  const bf16_t* vbase = vt + ((size_t)((b * 8 + h) * 64)) * vt_len + s * chunk;
  int kr0 = t >> 3, kc0g = ((t & 7) ^ (kr0 & 7)) * 8;
  int kr1 = kr0 + 32, kc1g = ((t & 7) ^ (kr1 & 7)) * 8;
  int n_kt = (chunk + 63) >> 6;
  async_copy16(kbase + (size_t)kr0 * 512 + kc0g, Ks[0] + w * 512);
  async_copy16(kbase + (size_t)kr1 * 512 + kc1g, Ks[0] + 2048 + w * 512);
  async_copy16(vbase + (size_t)kr0 * vt_len + kc0g, Vs[0] + w * 512);
  async_copy16(vbase + (size_t)kr1 * vt_len + kc1g, Vs[0] + 2048 + w * 512);
  for (int kt = 0; kt < n_kt; kt++) {
    int kc0 = kt * 64;
    __syncthreads();
    if (kt + 1 < n_kt) {
      int kn = (kt + 1) * 64;
      int nb = (kt + 1) & 1;
      async_copy16(kbase + (size_t)(kn + kr0) * 512 + kc0g, Ks[nb] + w * 512);
      async_copy16(kbase + (size_t)(kn + kr1) * 512 + kc1g, Ks[nb] + 2048 + w * 512);
      async_copy16(vbase + (size_t)kr0 * vt_len + kn + kc0g, Vs[nb] + w * 512);
      async_copy16(vbase + (size_t)kr1 * vt_len + kn + kc1g, Vs[nb] + 2048 + w * 512);
    }
    int cb = kt & 1;
    bf16x8 kf[4][2], vf[4][2];
#pragma unroll
    for (int kb = 0; kb < 4; kb++) {
      int rr = kb * 16 + l16;
#pragma unroll
      for (int c = 0; c < 2; c++) {
        int gi = (rr * 8 + ((quad + c * 4) ^ (rr & 7))) * 8;
        kf[kb][c] = *(const bf16x8*)&Ks[cb][gi];
        vf[kb][c] = *(const bf16x8*)&Vs[cb][gi];
      }
    }
    // S^T = K·Q^T : row = key, col = q (l16)
    f32x4 sx[4] = {z4, z4, z4, z4};
#pragma unroll
    for (int kb = 0; kb < 4; kb++) {
      sx[kb] = __builtin_amdgcn_mfma_f32_16x16x32_bf16(kf[kb][0], qa0, sx[kb], 0, 0, 0);
      sx[kb] = __builtin_amdgcn_mfma_f32_16x16x32_bf16(kf[kb][1], qa1, sx[kb], 0, 0, 0);
    }
    float rs = 0.f;
#pragma unroll
    for (int kb = 0; kb < 4; kb++)
#pragma unroll
      for (int r = 0; r < 4; r++) {
        float sv = sx[kb][r];
        if (MASK && (kc0 + kb * 16 + quad * 4 + r) >= n_k) sv = -1e30f;
        float pp = fast_exp2(sv);  // exp2(-1e30) = 0 for masked
        sx[kb][r] = pp;
        rs += pp;
      }
    rs += __shfl_xor(rs, 16);
    rs += __shfl_xor(rs, 32);
    l_i += rs;
    WAVE_LGKM();  // WAR
#pragma unroll
    for (int kb = 0; kb < 4; kb++) {
      bf16x4 pk;
#pragma unroll
      for (int r = 0; r < 4; r++) pk[r] = (bf16_t)sx[kb][r];
      *(bf16x4*)&p_lds[w][l16 * 72 + kb * 16 + quad * 4] = pk;
    }
    WAVE_LGKM();  // RAW
    bf16x8 pa0 = *(const bf16x8*)&p_lds[w][l16 * 72 + quad * 8];
    bf16x8 pa1 = *(const bf16x8*)&p_lds[w][l16 * 72 + 32 + quad * 8];
#pragma unroll
    for (int db = 0; db < 4; db++) {
      o[db] = __builtin_amdgcn_mfma_f32_16x16x32_bf16(vf[db][0], pa0, o[db], 0, 0, 0);
      o[db] = __builtin_amdgcn_mfma_f32_16x16x32_bf16(vf[db][1], pa1, o[db], 0, 0, 0);
    }
  }
  if (KSPLIT == 1) {
    float inv = 1.0f / l_i;
    bf16_t* orow = out + ((size_t)(b * 2304 + q0 + l16)) * 512 + h * 64 + quad * 4;
#pragma unroll
    for (int db = 0; db < 4; db++) {
      bf16x4 pk;
#pragma unroll
      for (int r = 0; r < 4; r++) pk[r] = (bf16_t)(o[db][r] * inv);
      *(bf16x4*)(orow + db * 16) = pk;
    }
  } else {
    float* orowf = Of + (size_t)s * TOKC + ((size_t)(b * 2304 + q0 + l16)) * 512 + h * 64 + quad * 4;
#pragma unroll
    for (int db = 0; db < 4; db++) *(f32x4*)(orowf + db * 16) = o[db];
    if ((t & 63) < 16)
      lp[(size_t)s * 4608 * 8 + ((size_t)(b * 2304 + q0 + l16)) * 8 + h] = l_i;
  }
}

// ---- reduce 3 K-split partials -> bf16 out ----
__global__ __launch_bounds__(256) void att_reduce_kernel(const float* __restrict__ Of,
                                                         const float* __restrict__ lp,
                                                         bf16_t* __restrict__ out) {
  size_t idx = (size_t)blockIdx.x * 256 + threadIdx.x;
  size_t base = idx * 8;
  int row = (int)(base >> 9);
  int col = (int)(base & 511);
  int h = col >> 6;
  size_t li = (size_t)row * 8 + h;
  float ls = lp[li] + lp[4608 * 8 + li] + lp[2 * 4608 * 8 + li];
  float inv = 1.0f / ls;
  f32x4 a0 = *(const f32x4*)(Of + base);
  f32x4 a1 = *(const f32x4*)(Of + base + 4);
  f32x4 b0 = *(const f32x4*)(Of + TOKC + base);
  f32x4 b1 = *(const f32x4*)(Of + TOKC + base + 4);
  f32x4 c0 = *(const f32x4*)(Of + 2 * TOKC + base);
  f32x4 c1 = *(const f32x4*)(Of + 2 * TOKC + base + 4);
  bf16x8 o;
#pragma unroll
  for (int j = 0; j < 4; j++) {
    o[j] = (bf16_t)((a0[j] + b0[j] + c0[j]) * inv);
    o[4 + j] = (bf16_t)((a1[j] + b1[j] + c1[j]) * inv);
  }
  *(bf16x8*)(out + base) = o;
}

extern "C" void kernel_launch(void* const* d_in, const int* in_sizes, int n_in,
                              void* d_out, int out_size, void* d_ws, size_t ws_size,
                              hipStream_t stream) {
  (void)out_size; (void)ws_size;
  char* p = (char*)d_ws;
  int* flag = (int*)p;
  float* stats = (float*)(p + 16);
  float* t32 = (float*)(p + 1024);
  bf16_t* conv = (bf16_t*)(p + 1024 + TOKC * 4);

  const int widx[10] = {4, 8, 9, 10, 11, 15, 18, 22, 24, 26};
  const int wK[10] = {512, 512, 512, 512, 512, 512, 512, 512, 2048, 512};
  const int wN[10] = {512, 512, 512, 512, 512, 512, 512, 4096, 512, 512};
  bool is_wt[28] = {};
  for (int i = 0; i < 10; i++) is_wt[widx[i]] = true;

  ConvArgs ca;
  int off = 0;
  int noff[28];
  for (int i = 0; i < 28; i++) {
    ca.src[i] = (i < n_in) ? d_in[i] : nullptr;
    ca.n[i] = (i < n_in && !is_wt[i]) ? in_sizes[i] : 0;
    ca.off[i] = off;
    noff[i] = off;
    int sz = (i < n_in) ? in_sizes[i] : 0;
    off += ((is_wt[i] ? 0 : sz) + 7) & ~7;
  }
  bf16_t* wt = conv + ((off + 7) & ~7);
  TransArgs ta;
  int woff = 0, wtoff[10];
  for (int i = 0; i < 10; i++) {
    ta.src[i] = d_in[widx[i]];
    ta.dst_off[i] = woff;
    wtoff[i] = woff;
    ta.K[i] = wK[i]; ta.N[i] = wN[i];
    woff += wK[i] * wN[i];
  }
  bf16_t* hn  = wt + woff;
  bf16_t* tb  = hn + TOKC;
  bf16_t* xnt = tb + TOKC;
  bf16_t* qb  = xnt + TOKC;
  bf16_t* kbuf = qb + TOKC;
  bf16_t* vtb = kbuf + TOKC;
  float*  Opart = (float*)(vtb + TOKC);          // 3 x TOKC fp32
  float*  lpart = Opart + 3 * TOKC;              // 3 x 4608*8 fp32
  bf16_t* ub2 = xnt;   // [4608,2048] spans xnt..vtb (all dead by ff1)
  bf16_t* ob  = xnt;

  const bf16_t* xb    = conv + noff[0];
  const bf16_t* ctxb  = conv + noff[1];
  const bf16_t* gn_g  = conv + noff[2];
  const bf16_t* gn_b  = conv + noff[3];
  const bf16_t* b_in  = conv + noff[5];
  const bf16_t* ln1_g = conv + noff[6];
  const bf16_t* ln1_b = conv + noff[7];
  const bf16_t* bo1   = conv + noff[12];
  const bf16_t* ln2_g = conv + noff[13];
  const bf16_t* ln2_b = conv + noff[14];
  const bf16_t* wk2   = conv + noff[16];
  const bf16_t* wv2   = conv + noff[17];
  const bf16_t* bo2   = conv + noff[19];
  const bf16_t* ln3_g = conv + noff[20];
  const bf16_t* ln3_b = conv + noff[21];
  const bf16_t* b_ff1 = conv + noff[23];
  const bf16_t* b_ff2 = conv + noff[25];
  const bf16_t* b_out = conv + noff[27];
  const bf16_t* wt_in  = wt + wtoff[0];
  const bf16_t* wt_q1  = wt + wtoff[1];
  const bf16_t* wt_k1  = wt + wtoff[2];
  const bf16_t* wt_v1  = wt + wtoff[3];
  const bf16_t* wt_o1  = wt + wtoff[4];
  const bf16_t* wt_q2  = wt + wtoff[5];
  const bf16_t* wt_o2  = wt + wtoff[6];
  const bf16_t* wt_ff1 = wt + wtoff[7];
  const bf16_t* wt_ff2 = wt + wtoff[8];
  const bf16_t* wt_out = wt + wtoff[9];

  probe_kernel<<<1, 64, 0, stream>>>(d_in[0], flag);
  convert_kernel<<<dim3(128, 28), 256, 0, stream>>>(ca, flag, conv);
  transpose_kernel<<<dim3(512, 10), 256, 0, stream>>>(ta, flag, wt);

  // GroupNorm + proj_in
  gn_stats_kernel<<<64, 256, 0, stream>>>(xb, stats);
  gn_apply_kernel<<<dim3(36, 8, 2), 256, 0, stream>>>(xb, stats, gn_g, gn_b, xnt);
  gemm64d_kernel<0, 1><<<dim3(8, 72), 256, 0, stream>>>(xnt, 512, wt_in, 512, 512, b_in, 1.f, t32, tb, nullptr, nullptr, nullptr, nullptr);
  // self-attention (K-split flash + reduce)
  ln_kernel<<<1152, 256, 0, stream>>>(t32, ln1_g, ln1_b, hn);
  qkv3_kernel<<<dim3(8, 72), 256, 0, stream>>>(hn, wt_q1, wt_k1, wt_v1, qb, kbuf, vtb);
  flash7_kernel<3, false><<<dim3(36, 16, 3), 256, 0, stream>>>(qb, kbuf, vtb, ob, Opart, lpart, 2304, 2304 * 512, 2304);
  att_reduce_kernel<<<1152, 256, 0, stream>>>(Opart, lpart, ob);
  gemm64d_kernel<0, 2><<<dim3(8, 72), 256, 0, stream>>>(ob, 512, wt_o1, 512, 512, bo1, 1.f, t32, tb, nullptr, nullptr, nullptr, nullptr);
  // cross-attention
  ln_kernel<<<1152, 256, 0, stream>>>(t32, ln2_g, ln2_b, hn);
  gemm64d_kernel<0, 0><<<dim3(8, 72), 256, 0, stream>>>(hn, 512, wt_q2, 512, 512, nullptr, QK_SCALE, nullptr, qb, nullptr, nullptr, nullptr, nullptr);
  kv2_kernel<<<dim3(8, 3, 2), 256, 0, stream>>>(ctxb, wk2, wv2, kbuf, vtb);
  flash7_kernel<1, true><<<dim3(36, 16, 1), 256, 0, stream>>>(qb, kbuf, vtb, ob, nullptr, nullptr, 77, 77 * 512, 128);
  gemm64d_kernel<0, 2><<<dim3(8, 72), 256, 0, stream>>>(ob, 512, wt_o2, 512, 512, bo2, 1.f, t32, tb, nullptr, nullptr, nullptr, nullptr);
  // GEGLU feed-forward
  ln_kernel<<<1152, 256, 0, stream>>>(t32, ln3_g, ln3_b, hn);
  ff1_kernel<<<dim3(16, 36), 256, 0, stream>>>(hn, wt_ff1, b_ff1, ub2);
  gemm64d_kernel<0, 2><<<dim3(8, 72), 256, 0, stream>>>(ub2, 2048, wt_ff2, 2048, 512, b_ff2, 1.f, t32, tb, nullptr, nullptr, nullptr, nullptr);
  // proj_out: dtype-adaptive output + residual
  gemm64d_kernel<1, 3><<<dim3(8, 72), 256, 0, stream>>>(tb, 512, wt_out, 512, 512, b_out, 1.f, nullptr, (bf16_t*)d_out, xb, (const float*)d_in[0], (float*)d_out, flag);
}

// Round 11
// 403.605 us; speedup vs baseline: 1.0645x; 1.0645x over previous
//
#include <hip/hip_runtime.h>
#include <hip/hip_bf16.h>

typedef __bf16 bf16_t;
typedef __bf16 bf16x4 __attribute__((ext_vector_type(4)));
typedef __bf16 bf16x8 __attribute__((ext_vector_type(8)));
typedef float f32x4 __attribute__((ext_vector_type(4)));

static __device__ __forceinline__ bf16x8 bzero8() {
  bf16x8 v;
#pragma unroll
  for (int j = 0; j < 8; j++) v[j] = (bf16_t)0.f;
  return v;
}

// async global->LDS, 16B per lane; LDS dest = wave-uniform base + lane*16
static __device__ __forceinline__ void async_copy16(const bf16_t* g, bf16_t* l) {
  __builtin_amdgcn_global_load_lds((const __attribute__((address_space(1))) void*)g,
                                   (__attribute__((address_space(3))) void*)l,
                                   16, 0, 0);
}
#define WAVE_LGKM() asm volatile("s_waitcnt lgkmcnt(0)" ::: "memory")

static __device__ __forceinline__ float fast_exp2(float x) {
  float r;
  asm volatile("v_exp_f32 %0, %1" : "=v"(r) : "v"(x));
  return r;
}

#define QK_SCALE 0.18033688f  /* 0.125 * log2(e) */
#define TOKC ((size_t)4608 * 512)

// ---------------- dtype probe ----------------
__global__ void probe_kernel(const void* x, int* flag) {
  if (threadIdx.x != 0 || blockIdx.x != 0) return;
  const unsigned short* u = (const unsigned short*)x;
  int insane = 0;
  for (int j = 0; j < 512; j++) {
    unsigned short h = u[j];
    int e = (h >> 7) & 0xFF;
    if (e == 0xFF || e > 140 || (e != 0 && e < 100)) insane++;
  }
  *flag = (insane > 16) ? 1 : 0;  // 1 => fp32 I/O
}

// ---------------- convert inputs to bf16 (vectorized x4) ----------------
struct ConvArgs { const void* src[28]; int n[28]; int off[28]; };
__global__ __launch_bounds__(256) void convert_kernel(ConvArgs a, const int* flag,
                                                      bf16_t* dst) {
  int i = blockIdx.y;
  if (i >= 28) return;
  int n = a.n[i];
  if (n == 0) return;
  const void* s = a.src[i];
  bf16_t* d = dst + a.off[i];
  bool f32 = (*flag != 0);
  int n4 = n >> 2;
  for (int j = blockIdx.x * 256 + threadIdx.x; j < n4; j += gridDim.x * 256) {
    bf16x4 o;
    if (f32) {
      float4 v = ((const float4*)s)[j];
      o[0] = (bf16_t)v.x; o[1] = (bf16_t)v.y; o[2] = (bf16_t)v.z; o[3] = (bf16_t)v.w;
    } else {
      o = ((const bf16x4*)s)[j];
    }
    ((bf16x4*)d)[j] = o;
  }
  int base = n4 << 2;
  int j = base + blockIdx.x * 256 + threadIdx.x;
  if (j < n) {
    float v = f32 ? ((const float*)s)[j] : (float)((const bf16_t*)s)[j];
    d[j] = (bf16_t)v;
  }
}

// -------- batched weight transpose [K][N] -> [N][K], reads raw dtype --------
struct TransArgs { const void* src[10]; int dst_off[10]; int K[10]; int N[10]; };
__global__ __launch_bounds__(256) void transpose_kernel(TransArgs ta, const int* flag,
                                                        bf16_t* __restrict__ wt) {
  int wi = blockIdx.y;
  int K = ta.K[wi], N = ta.N[wi];
  int tiles_n = N >> 6;
  int tile = blockIdx.x;
  if (tile >= tiles_n * (K >> 6)) return;
  int tk = tile / tiles_n, tn = tile - tk * tiles_n;
  int k0 = tk * 64, n0 = tn * 64;
  bf16_t* dst = wt + ta.dst_off[wi];
  bool f32 = (*flag != 0);
  __shared__ bf16_t tl[64][66];
  int t = threadIdx.x;
  int r = t >> 2, c = (t & 3) * 16;
  if (f32) {
    const float* src = (const float*)ta.src[wi] + (size_t)(k0 + r) * N + n0 + c;
#pragma unroll
    for (int q = 0; q < 4; q++) {
      float4 v = *(const float4*)(src + q * 4);
      tl[r][c + q * 4 + 0] = (bf16_t)v.x;
      tl[r][c + q * 4 + 1] = (bf16_t)v.y;
      tl[r][c + q * 4 + 2] = (bf16_t)v.z;
      tl[r][c + q * 4 + 3] = (bf16_t)v.w;
    }
  } else {
    const bf16_t* src = (const bf16_t*)ta.src[wi] + (size_t)(k0 + r) * N + n0 + c;
    bf16x8 v0 = *(const bf16x8*)(src);
    bf16x8 v1 = *(const bf16x8*)(src + 8);
#pragma unroll
    for (int j = 0; j < 8; j++) { tl[r][c + j] = v0[j]; tl[r][c + 8 + j] = v1[j]; }
  }
  __syncthreads();
  bf16x8 o0, o1;
#pragma unroll
  for (int j = 0; j < 8; j++) { o0[j] = tl[c + j][r]; o1[j] = tl[c + 8 + j][r]; }
  *(bf16x8*)(dst + (size_t)(n0 + r) * K + k0 + c) = o0;
  *(bf16x8*)(dst + (size_t)(n0 + r) * K + k0 + c + 8) = o1;
}

// ---------------- GroupNorm stats ----------------
__global__ __launch_bounds__(256) void gn_stats_kernel(const bf16_t* __restrict__ x,
                                                       float* __restrict__ stats) {
  const bf16x8* base = (const bf16x8*)(x + (size_t)blockIdx.x * 36864);
  float s = 0.f, ss = 0.f;
  for (int i = threadIdx.x; i < 4608; i += 256) {
    bf16x8 v = base[i];
#pragma unroll
    for (int j = 0; j < 8; j++) { float f = (float)v[j]; s += f; ss += f * f; }
  }
  __shared__ float red[8];
#pragma unroll
  for (int off = 32; off > 0; off >>= 1) { s += __shfl_down(s, off); ss += __shfl_down(ss, off); }
  int wid = threadIdx.x >> 6;
  if ((threadIdx.x & 63) == 0) { red[wid] = s; red[4 + wid] = ss; }
  __syncthreads();
  if (threadIdx.x == 0) {
    float S = red[0] + red[1] + red[2] + red[3];
    float SS = red[4] + red[5] + red[6] + red[7];
    const float inv = 1.0f / 36864.0f;
    float mean = S * inv;
    float var = SS * inv - mean * mean;
    stats[blockIdx.x * 2] = mean;
    stats[blockIdx.x * 2 + 1] = rsqrtf(fmaxf(var, 0.f) + 1e-6f);
  }
}

// GN normalize + tiled transpose [B,C,HW] -> xnt[(b*2304+p)][c]
__global__ __launch_bounds__(256) void gn_apply_kernel(const bf16_t* __restrict__ x,
                                                       const float* __restrict__ stats,
                                                       const bf16_t* __restrict__ g,
                                                       const bf16_t* __restrict__ bb,
                                                       bf16_t* __restrict__ xnt) {
  int p0 = blockIdx.x * 64, c0 = blockIdx.y * 64, bz = blockIdx.z;
  __shared__ bf16_t tl[64][66];
  int t = threadIdx.x;
  int r = t >> 2, cc = (t & 3) * 16;
  int c = c0 + r;
  float mean = stats[(bz * 32 + (c >> 4)) * 2];
  float rstd = stats[(bz * 32 + (c >> 4)) * 2 + 1];
  float gg = (float)g[c], bbv = (float)bb[c];
  const bf16_t* row = x + ((size_t)(bz * 512 + c)) * 2304 + p0 + cc;
  bf16x8 v0 = *(const bf16x8*)(row);
  bf16x8 v1 = *(const bf16x8*)(row + 8);
#pragma unroll
  for (int j = 0; j < 8; j++) {
    tl[r][cc + j] = (bf16_t)(((float)v0[j] - mean) * rstd * gg + bbv);
    tl[r][cc + 8 + j] = (bf16_t)(((float)v1[j] - mean) * rstd * gg + bbv);
  }
  __syncthreads();
  bf16x8 o0, o1;
#pragma unroll
  for (int j = 0; j < 8; j++) { o0[j] = tl[cc + j][r]; o1[j] = tl[cc + 8 + j][r]; }
  bf16_t* orow = xnt + ((size_t)(bz * 2304 + p0 + r)) * 512 + c0 + cc;
  *(bf16x8*)(orow) = o0;
  *(bf16x8*)(orow + 8) = o1;
}

// ---------------- LayerNorm ----------------
__global__ __launch_bounds__(256) void ln_kernel(const float* __restrict__ in,
                                                 const bf16_t* __restrict__ g,
                                                 const bf16_t* __restrict__ b,
                                                 bf16_t* __restrict__ out) {
  int tok = blockIdx.x * 4 + (threadIdx.x >> 6);
  int lane = threadIdx.x & 63;
  const float* row = in + (size_t)tok * 512 + lane * 8;
  float f[8];
  float s = 0.f, ss = 0.f;
#pragma unroll
  for (int j = 0; j < 8; j++) { f[j] = row[j]; s += f[j]; ss += f[j] * f[j]; }
#pragma unroll
  for (int off = 32; off > 0; off >>= 1) { s += __shfl_xor(s, off); ss += __shfl_xor(ss, off); }
  float mean = s * (1.0f / 512.0f);
  float var = ss * (1.0f / 512.0f) - mean * mean;
  float rstd = rsqrtf(fmaxf(var, 0.f) + 1e-5f);
  bf16x8 gv = *(const bf16x8*)(g + lane * 8);
  bf16x8 bv = *(const bf16x8*)(b + lane * 8);
  bf16x8 o;
#pragma unroll
  for (int j = 0; j < 8; j++) o[j] = (bf16_t)((f[j] - mean) * rstd * (float)gv[j] + (float)bv[j]);
  *(bf16x8*)(out + (size_t)tok * 512 + lane * 8) = o;
}

// ============ 64x64 dbuf GEMM, BK=64, 32x32 wave-tiles (proven) ======
template <int SMODE, int MODE>
__global__ __launch_bounds__(256) void gemm64d_kernel(
    const bf16_t* __restrict__ A, int lda,
    const bf16_t* __restrict__ Bt, int K, int N,
    const bf16_t* __restrict__ bias, float oscale,
    float* __restrict__ t32, bf16_t* __restrict__ C,
    const bf16_t* __restrict__ resb, const float* __restrict__ resf,
    float* __restrict__ Cf, const int* dflag) {
  __shared__ bf16_t As[2][4096];
  __shared__ bf16_t Bs[2][4096];
  int t = threadIdx.x, w = t >> 6, quad = (t >> 4) & 3, l16 = t & 15;
  int m0 = blockIdx.y * 64, n0 = blockIdx.x * 64;
  int wm = (w >> 1) * 32, wn = (w & 1) * 32;
  const f32x4 z4 = {0.f, 0.f, 0.f, 0.f};
  f32x4 acc[2][2] = {{z4, z4}, {z4, z4}};
  int r0 = t >> 3, c0 = ((t & 7) ^ (r0 & 7)) * 8;
  int r1 = r0 + 32, c1 = ((t & 7) ^ (r1 & 7)) * 8;
  const bf16_t* Ar0 = A + (size_t)(m0 + r0) * lda + c0;
  const bf16_t* Ar1 = A + (size_t)(m0 + r1) * lda + c1;
  const bf16_t* Br0 = Bt + (size_t)(n0 + r0) * K + c0;
  const bf16_t* Br1 = Bt + (size_t)(n0 + r1) * K + c1;
  int niter = K >> 6;
  async_copy16(Ar0, As[0] + w * 512);
  async_copy16(Ar1, As[0] + 2048 + w * 512);
  async_copy16(Br0, Bs[0] + w * 512);
  async_copy16(Br1, Bs[0] + 2048 + w * 512);
  for (int it = 0; it < niter; it++) {
    __syncthreads();
    if (it + 1 < niter) {
      int k0 = (it + 1) << 6;
      int nb = (it + 1) & 1;
      async_copy16(Ar0 + k0, As[nb] + w * 512);
      async_copy16(Ar1 + k0, As[nb] + 2048 + w * 512);
      async_copy16(Br0 + k0, Bs[nb] + w * 512);
      async_copy16(Br1 + k0, Bs[nb] + 2048 + w * 512);
    }
    int cb = it & 1;
    bf16x8 af[2][2], bff[2][2];
#pragma unroll
    for (int mi = 0; mi < 2; mi++) {
      int rr = wm + mi * 16 + l16;
      af[mi][0] = *(const bf16x8*)&As[cb][(rr * 8 + (quad ^ (rr & 7))) * 8];
      af[mi][1] = *(const bf16x8*)&As[cb][(rr * 8 + ((quad + 4) ^ (rr & 7))) * 8];
    }
#pragma unroll
    for (int ni = 0; ni < 2; ni++) {
      int rr = wn + ni * 16 + l16;
      bff[ni][0] = *(const bf16x8*)&Bs[cb][(rr * 8 + (quad ^ (rr & 7))) * 8];
      bff[ni][1] = *(const bf16x8*)&Bs[cb][(rr * 8 + ((quad + 4) ^ (rr & 7))) * 8];
    }
#pragma unroll
    for (int mi = 0; mi < 2; mi++)
#pragma unroll
      for (int ni = 0; ni < 2; ni++) {
        acc[mi][ni] = __builtin_amdgcn_mfma_f32_16x16x32_bf16(af[mi][0], bff[ni][0], acc[mi][ni], 0, 0, 0);
        acc[mi][ni] = __builtin_amdgcn_mfma_f32_16x16x32_bf16(af[mi][1], bff[ni][1], acc[mi][ni], 0, 0, 0);
      }
  }
  const bool f32m = (MODE == 3) && (*dflag != 0);
#pragma unroll
  for (int mi = 0; mi < 2; mi++)
#pragma unroll
    for (int ni = 0; ni < 2; ni++) {
      int col = n0 + wn + ni * 16 + l16;
      float bv = bias ? (float)bias[col] : 0.f;
#pragma unroll
      for (int r = 0; r < 4; r++) {
        int row = m0 + wm + mi * 16 + quad * 4 + r;
        float v = acc[mi][ni][r] + bv;
        size_t addr;
        if (SMODE == 0) {
          addr = (size_t)row * N + col;
        } else {
          int b2 = row / 2304; int p = row - b2 * 2304;
          addr = ((size_t)(b2 * 512 + col)) * 2304 + p;
        }
        if (MODE == 0) C[addr] = (bf16_t)(v * oscale);
        else if (MODE == 1) { t32[addr] = v; C[addr] = (bf16_t)v; }
        else if (MODE == 2) { v += t32[addr]; t32[addr] = v; C[addr] = (bf16_t)v; }
        else {
          v += f32m ? resf[addr] : (float)resb[addr];
          if (f32m) Cf[addr] = v; else C[addr] = (bf16_t)v;
        }
      }
    }
}

// ---- fused QKV3: ONE dispatch, A staged once, 3 B tiles, 3 outputs ----
__global__ __launch_bounds__(256) void qkv3_kernel(
    const bf16_t* __restrict__ A,
    const bf16_t* __restrict__ BtQ, const bf16_t* __restrict__ BtK,
    const bf16_t* __restrict__ BtV,
    bf16_t* __restrict__ Qo, bf16_t* __restrict__ Ko, bf16_t* __restrict__ Vt) {
  __shared__ bf16_t As[2][4096];
  __shared__ bf16_t Bs[3][2][4096];
  int t = threadIdx.x, w = t >> 6, quad = (t >> 4) & 3, l16 = t & 15;
  int m0 = blockIdx.y * 64, n0 = blockIdx.x * 64;
  int wm = (w >> 1) * 32, wn = (w & 1) * 32;
  const f32x4 z4 = {0.f, 0.f, 0.f, 0.f};
  f32x4 acc[3][2][2];
#pragma unroll
  for (int z = 0; z < 3; z++)
#pragma unroll
    for (int mi = 0; mi < 2; mi++)
#pragma unroll
      for (int ni = 0; ni < 2; ni++) acc[z][mi][ni] = z4;
  int r0 = t >> 3, c0 = ((t & 7) ^ (r0 & 7)) * 8;
  int r1 = r0 + 32, c1 = ((t & 7) ^ (r1 & 7)) * 8;
  const bf16_t* Ar0 = A + (size_t)(m0 + r0) * 512 + c0;
  const bf16_t* Ar1 = A + (size_t)(m0 + r1) * 512 + c1;
  const bf16_t* Bw[3] = {BtQ, BtK, BtV};
  const bf16_t* Br0[3];
  const bf16_t* Br1[3];
#pragma unroll
  for (int z = 0; z < 3; z++) {
    Br0[z] = Bw[z] + (size_t)(n0 + r0) * 512 + c0;
    Br1[z] = Bw[z] + (size_t)(n0 + r1) * 512 + c1;
  }
  async_copy16(Ar0, As[0] + w * 512);
  async_copy16(Ar1, As[0] + 2048 + w * 512);
#pragma unroll
  for (int z = 0; z < 3; z++) {
    async_copy16(Br0[z], Bs[z][0] + w * 512);
    async_copy16(Br1[z], Bs[z][0] + 2048 + w * 512);
  }
  for (int it = 0; it < 8; it++) {
    __syncthreads();
    if (it + 1 < 8) {
      int k0 = (it + 1) << 6;
      int nb = (it + 1) & 1;
      async_copy16(Ar0 + k0, As[nb] + w * 512);
      async_copy16(Ar1 + k0, As[nb] + 2048 + w * 512);
#pragma unroll
      for (int z = 0; z < 3; z++) {
        async_copy16(Br0[z] + k0, Bs[z][nb] + w * 512);
        async_copy16(Br1[z] + k0, Bs[z][nb] + 2048 + w * 512);
      }
    }
    int cb = it & 1;
    bf16x8 af[2][2];
#pragma unroll
    for (int mi = 0; mi < 2; mi++) {
      int rr = wm + mi * 16 + l16;
      af[mi][0] = *(const bf16x8*)&As[cb][(rr * 8 + (quad ^ (rr & 7))) * 8];
      af[mi][1] = *(const bf16x8*)&As[cb][(rr * 8 + ((quad + 4) ^ (rr & 7))) * 8];
    }
#pragma unroll
    for (int z = 0; z < 3; z++) {
      bf16x8 bff[2][2];
#pragma unroll
      for (int ni = 0; ni < 2; ni++) {
        int rr = wn + ni * 16 + l16;
        bff[ni][0] = *(const bf16x8*)&Bs[z][cb][(rr * 8 + (quad ^ (rr & 7))) * 8];
        bff[ni][1] = *(const bf16x8*)&Bs[z][cb][(rr * 8 + ((quad + 4) ^ (rr & 7))) * 8];
      }
#pragma unroll
      for (int mi = 0; mi < 2; mi++)
#pragma unroll
        for (int ni = 0; ni < 2; ni++) {
          acc[z][mi][ni] = __builtin_amdgcn_mfma_f32_16x16x32_bf16(af[mi][0], bff[ni][0], acc[z][mi][ni], 0, 0, 0);
          acc[z][mi][ni] = __builtin_amdgcn_mfma_f32_16x16x32_bf16(af[mi][1], bff[ni][1], acc[z][mi][ni], 0, 0, 0);
        }
    }
  }
#pragma unroll
  for (int mi = 0; mi < 2; mi++)
#pragma unroll
    for (int ni = 0; ni < 2; ni++) {
      int col = n0 + wn + ni * 16 + l16;
#pragma unroll
      for (int r = 0; r < 4; r++) {
        int row = m0 + wm + mi * 16 + quad * 4 + r;
        Qo[(size_t)row * 512 + col] = (bf16_t)(acc[0][mi][ni][r] * QK_SCALE);
        Ko[(size_t)row * 512 + col] = (bf16_t)acc[1][mi][ni][r];
        int b2 = row / 2304; int p = row - b2 * 2304;
        Vt[((size_t)(b2 * 512 + col)) * 2304 + p] = (bf16_t)acc[2][mi][ni][r];
      }
    }
}

// ------- fused GEGLU ff1 (round-9 proven: 64x64, BK=64, LDS dbuf) -------
__global__ __launch_bounds__(256) void ff1_kernel(const bf16_t* __restrict__ A,   // [4608,512]
                                                  const bf16_t* __restrict__ Bt,  // [4096,512]
                                                  const bf16_t* __restrict__ bias,
                                                  bf16_t* __restrict__ U) {       // [4608,2048]
  __shared__ bf16_t As[2][4096];
  __shared__ bf16_t Ba[2][4096];
  __shared__ bf16_t Bg[2][4096];
  int t = threadIdx.x, w = t >> 6, quad = (t >> 4) & 3, l16 = t & 15;
  int m0 = blockIdx.y * 64, n0 = blockIdx.x * 64;
  int wm = (w >> 1) * 32, wn = (w & 1) * 32;
  const f32x4 z4 = {0.f, 0.f, 0.f, 0.f};
  f32x4 aa[2][2] = {{z4, z4}, {z4, z4}};
  f32x4 ag[2][2] = {{z4, z4}, {z4, z4}};
  int r0 = t >> 3, c0 = ((t & 7) ^ (r0 & 7)) * 8;
  int r1 = r0 + 32, c1 = ((t & 7) ^ (r1 & 7)) * 8;
  const bf16_t* Ar0 = A + (size_t)(m0 + r0) * 512 + c0;
  const bf16_t* Ar1 = A + (size_t)(m0 + r1) * 512 + c1;
  const bf16_t* Ba0 = Bt + (size_t)(n0 + r0) * 512 + c0;
  const bf16_t* Ba1 = Bt + (size_t)(n0 + r1) * 512 + c1;
  const bf16_t* Bg0 = Bt + (size_t)(2048 + n0 + r0) * 512 + c0;
  const bf16_t* Bg1 = Bt + (size_t)(2048 + n0 + r1) * 512 + c1;
  async_copy16(Ar0, As[0] + w * 512);
  async_copy16(Ar1, As[0] + 2048 + w * 512);
  async_copy16(Ba0, Ba[0] + w * 512);
  async_copy16(Ba1, Ba[0] + 2048 + w * 512);
  async_copy16(Bg0, Bg[0] + w * 512);
  async_copy16(Bg1, Bg[0] + 2048 + w * 512);
  for (int it = 0; it < 8; it++) {
    __syncthreads();
    if (it + 1 < 8) {
      int k0 = (it + 1) << 6;
      int nb = (it + 1) & 1;
      async_copy16(Ar0 + k0, As[nb] + w * 512);
      async_copy16(Ar1 + k0, As[nb] + 2048 + w * 512);
      async_copy16(Ba0 + k0, Ba[nb] + w * 512);
      async_copy16(Ba1 + k0, Ba[nb] + 2048 + w * 512);
      async_copy16(Bg0 + k0, Bg[nb] + w * 512);
      async_copy16(Bg1 + k0, Bg[nb] + 2048 + w * 512);
    }
    int cb = it & 1;
    bf16x8 af[2][2], ba[2][2], bg[2][2];
#pragma unroll
    for (int mi = 0; mi < 2; mi++) {
      int rr = wm + mi * 16 + l16;
      af[mi][0] = *(const bf16x8*)&As[cb][(rr * 8 + (quad ^ (rr & 7))) * 8];
      af[mi][1] = *(const bf16x8*)&As[cb][(rr * 8 + ((quad + 4) ^ (rr & 7))) * 8];
    }
#pragma unroll
    for (int ni = 0; ni < 2; ni++) {
      int rr = wn + ni * 16 + l16;
      int o0 = (rr * 8 + (quad ^ (rr & 7))) * 8;
      int o1 = (rr * 8 + ((quad + 4) ^ (rr & 7))) * 8;
      ba[ni][0] = *(const bf16x8*)&Ba[cb][o0];
      ba[ni][1] = *(const bf16x8*)&Ba[cb][o1];
      bg[ni][0] = *(const bf16x8*)&Bg[cb][o0];
      bg[ni][1] = *(const bf16x8*)&Bg[cb][o1];
    }
#pragma unroll
    for (int mi = 0; mi < 2; mi++)
#pragma unroll
      for (int ni = 0; ni < 2; ni++) {
        aa[mi][ni] = __builtin_amdgcn_mfma_f32_16x16x32_bf16(af[mi][0], ba[ni][0], aa[mi][ni], 0, 0, 0);
        aa[mi][ni] = __builtin_amdgcn_mfma_f32_16x16x32_bf16(af[mi][1], ba[ni][1], aa[mi][ni], 0, 0, 0);
        ag[mi][ni] = __builtin_amdgcn_mfma_f32_16x16x32_bf16(af[mi][0], bg[ni][0], ag[mi][ni], 0, 0, 0);
        ag[mi][ni] = __builtin_amdgcn_mfma_f32_16x16x32_bf16(af[mi][1], bg[ni][1], ag[mi][ni], 0, 0, 0);
      }
  }
#pragma unroll
  for (int mi = 0; mi < 2; mi++)
#pragma unroll
    for (int ni = 0; ni < 2; ni++) {
      int col = n0 + wn + ni * 16 + l16;
      float bba = (float)bias[col], bbg = (float)bias[col + 2048];
#pragma unroll
      for (int r = 0; r < 4; r++) {
        int row = m0 + wm + mi * 16 + quad * 4 + r;
        float a = aa[mi][ni][r] + bba;
        float g = ag[mi][ni][r] + bbg;
        float gl = 0.5f * g * (1.0f + erff(g * 0.70710678118654752f));
        U[(size_t)row * 2048 + col] = (bf16_t)(a * gl);
      }
    }
}

// -------- cross K/V merged (z=0: K->kbuf; z=1: V->vtb), M=154, K=768 --------
__global__ __launch_bounds__(256) void kv2_kernel(const bf16_t* __restrict__ A,
                                                  const bf16_t* __restrict__ Bk,
                                                  const bf16_t* __restrict__ Bv,
                                                  bf16_t* __restrict__ Ck,
                                                  bf16_t* __restrict__ Cv) {
  const int M = 154, N = 512, K = 768;
  int z = blockIdx.z;
  const bf16_t* B = z ? Bv : Bk;
  __shared__ alignas(16) bf16_t As[64][40];
  __shared__ alignas(16) bf16_t Bs[64][40];
  int t = threadIdx.x;
  int m0 = blockIdx.y * 64, n0 = blockIdx.x * 64;
  int w = t >> 6, lane = t & 63, quad = lane >> 4, l16 = lane & 15;
  int ar = t >> 2, ac = (t & 3) * 8;
  int br = t >> 3, bc = (t & 7) * 8;
  const f32x4 z4 = {0.f, 0.f, 0.f, 0.f};
  f32x4 acc[4] = {z4, z4, z4, z4};
  int gm = m0 + ar;
  const bool a_ok = gm < M;
  for (int k0 = 0; k0 < K; k0 += 32) {
    bf16x8 av = a_ok ? *(const bf16x8*)(A + (size_t)gm * K + k0 + ac) : bzero8();
    bf16x8 bv = *(const bf16x8*)(B + (size_t)(k0 + br) * N + n0 + bc);
    __syncthreads();
    *(bf16x8*)(&As[ar][ac]) = av;
#pragma unroll
    for (int j = 0; j < 8; j++) Bs[bc + j][br] = bv[j];
    __syncthreads();
    bf16x8 afrag = *(const bf16x8*)(&As[w * 16 + l16][quad * 8]);
#pragma unroll
    for (int kb = 0; kb < 4; kb++) {
      bf16x8 bfrag = *(const bf16x8*)(&Bs[kb * 16 + l16][quad * 8]);
      acc[kb] = __builtin_amdgcn_mfma_f32_16x16x32_bf16(afrag, bfrag, acc[kb], 0, 0, 0);
    }
  }
#pragma unroll
  for (int kb = 0; kb < 4; kb++) {
    int col = n0 + kb * 16 + l16;
#pragma unroll
    for (int r = 0; r < 4; r++) {
      int row = m0 + w * 16 + quad * 4 + r;
      if (row < M) {
        float v = acc[kb][r];
        if (z == 0) Ck[(size_t)row * N + col] = (bf16_t)v;
        else {
          int b2 = row / 77; int p = row - b2 * 77;
          Cv[((size_t)(b2 * 512 + col)) * 128 + p] = (bf16_t)v;
        }
      }
    }
  }
}

// ---- Flash v7: K-split (additive no-max softmax), 16 q/wave, dbuf staging ----
template <int KSPLIT, bool MASK>
__global__ __launch_bounds__(256) void flash7_kernel(const bf16_t* __restrict__ q,
                                                     const bf16_t* __restrict__ kk,
                                                     const bf16_t* __restrict__ vt,
                                                     bf16_t* __restrict__ out,
                                                     float* __restrict__ Of,
                                                     float* __restrict__ lp,
                                                     int n_k, int kv_bstride, int vt_len) {
  __shared__ bf16_t Ks[2][4096];
  __shared__ bf16_t Vs[2][4096];
  __shared__ bf16_t p_lds[4][16 * 72];
  int t = threadIdx.x, w = t >> 6, quad = (t >> 4) & 3, l16 = t & 15;
  int b = blockIdx.y >> 3, h = blockIdx.y & 7;
  int s = (KSPLIT > 1) ? blockIdx.z : 0;
  int chunk = n_k / KSPLIT;
  int q0 = blockIdx.x * 64 + w * 16;
  const bf16_t* qrow = q + ((size_t)(b * 2304 + q0 + l16)) * 512 + h * 64 + quad * 8;
  bf16x8 qa0 = *(const bf16x8*)(qrow);
  bf16x8 qa1 = *(const bf16x8*)(qrow + 32);
  const f32x4 z4 = {0.f, 0.f, 0.f, 0.f};
  f32x4 o[4] = {z4, z4, z4, z4};
  float l_i = 0.f;
  const bf16_t* kbase = kk + (size_t)b * kv_bstride + h * 64 + (size_t)s * chunk * 512;
  const bf16_t* vbase = vt + ((size_t)((b * 8 + h) * 64)) * vt_len + s * chunk;
  int kr0 = t >> 3, kc0g = ((t & 7) ^ (kr0 & 7)) * 8;
  int kr1 = kr0 + 32, kc1g = ((t & 7) ^ (kr1 & 7)) * 8;
  int n_kt = (chunk + 63) >> 6;
  async_copy16(kbase + (size_t)kr0 * 512 + kc0g, Ks[0] + w * 512);
  async_copy16(kbase + (size_t)kr1 * 512 + kc1g, Ks[0] + 2048 + w * 512);
  async_copy16(vbase + (size_t)kr0 * vt_len + kc0g, Vs[0] + w * 512);
  async_copy16(vbase + (size_t)kr1 * vt_len + kc1g, Vs[0] + 2048 + w * 512);
  for (int kt = 0; kt < n_kt; kt++) {
    int kc0 = kt * 64;
    __syncthreads();
    if (kt + 1 < n_kt) {
      int kn = (kt + 1) * 64;
      int nb = (kt + 1) & 1;
      async_copy16(kbase + (size_t)(kn + kr0) * 512 + kc0g, Ks[nb] + w * 512);
      async_copy16(kbase + (size_t)(kn + kr1) * 512 + kc1g, Ks[nb] + 2048 + w * 512);
      async_copy16(vbase + (size_t)kr0 * vt_len + kn + kc0g, Vs[nb] + w * 512);
      async_copy16(vbase + (size_t)kr1 * vt_len + kn + kc1g, Vs[nb] + 2048 + w * 512);
    }
    int cb = kt & 1;
    bf16x8 kf[4][2], vf[4][2];
#pragma unroll
    for (int kb = 0; kb < 4; kb++) {
      int rr = kb * 16 + l16;
#pragma unroll
      for (int c = 0; c < 2; c++) {
        int gi = (rr * 8 + ((quad + c * 4) ^ (rr & 7))) * 8;
        kf[kb][c] = *(const bf16x8*)&Ks[cb][gi];
        vf[kb][c] = *(const bf16x8*)&Vs[cb][gi];
      }
    }
    // S^T = K·Q^T : row = key, col = q (l16)
    f32x4 sx[4] = {z4, z4, z4, z4};
#pragma unroll
    for (int kb = 0; kb < 4; kb++) {
      sx[kb] = __builtin_amdgcn_mfma_f32_16x16x32_bf16(kf[kb][0], qa0, sx[kb], 0, 0, 0);
      sx[kb] = __builtin_amdgcn_mfma_f32_16x16x32_bf16(kf[kb][1], qa1, sx[kb], 0, 0, 0);
    }
    float rs = 0.f;
#pragma unroll
    for (int kb = 0; kb < 4; kb++)
#pragma unroll
      for (int r = 0; r < 4; r++) {
        float sv = sx[kb][r];
        if (MASK && (kc0 + kb * 16 + quad * 4 + r) >= n_k) sv = -1e30f;
        float pp = fast_exp2(sv);  // exp2(-1e30) = 0 for masked
        sx[kb][r] = pp;
        rs += pp;
      }
    rs += __shfl_xor(rs, 16);
    rs += __shfl_xor(rs, 32);
    l_i += rs;
    WAVE_LGKM();  // WAR
#pragma unroll
    for (int kb = 0; kb < 4; kb++) {
      bf16x4 pk;
#pragma unroll
      for (int r = 0; r < 4; r++) pk[r] = (bf16_t)sx[kb][r];
      *(bf16x4*)&p_lds[w][l16 * 72 + kb * 16 + quad * 4] = pk;
    }
    WAVE_LGKM();  // RAW
    bf16x8 pa0 = *(const bf16x8*)&p_lds[w][l16 * 72 + quad * 8];
    bf16x8 pa1 = *(const bf16x8*)&p_lds[w][l16 * 72 + 32 + quad * 8];
#pragma unroll
    for (int db = 0; db < 4; db++) {
      o[db] = __builtin_amdgcn_mfma_f32_16x16x32_bf16(vf[db][0], pa0, o[db], 0, 0, 0);
      o[db] = __builtin_amdgcn_mfma_f32_16x16x32_bf16(vf[db][1], pa1, o[db], 0, 0, 0);
    }
  }
  if (KSPLIT == 1) {
    float inv = 1.0f / l_i;
    bf16_t* orow = out + ((size_t)(b * 2304 + q0 + l16)) * 512 + h * 64 + quad * 4;
#pragma unroll
    for (int db = 0; db < 4; db++) {
      bf16x4 pk;
#pragma unroll
      for (int r = 0; r < 4; r++) pk[r] = (bf16_t)(o[db][r] * inv);
      *(bf16x4*)(orow + db * 16) = pk;
    }
  } else {
    float* orowf = Of + (size_t)s * TOKC + ((size_t)(b * 2304 + q0 + l16)) * 512 + h * 64 + quad * 4;
#pragma unroll
    for (int db = 0; db < 4; db++) *(f32x4*)(orowf + db * 16) = o[db];
    if ((t & 63) < 16)
      lp[(size_t)s * 4608 * 8 + ((size_t)(b * 2304 + q0 + l16)) * 8 + h] = l_i;
  }
}

// ---- reduce 3 K-split partials -> bf16 out ----
__global__ __launch_bounds__(256) void att_reduce_kernel(const float* __restrict__ Of,
                                                         const float* __restrict__ lp,
                                                         bf16_t* __restrict__ out) {
  size_t idx = (size_t)blockIdx.x * 256 + threadIdx.x;
  size_t base = idx * 8;
  int row = (int)(base >> 9);
  int col = (int)(base & 511);
  int h = col >> 6;
  size_t li = (size_t)row * 8 + h;
  float ls = lp[li] + lp[4608 * 8 + li] + lp[2 * 4608 * 8 + li];
  float inv = 1.0f / ls;
  f32x4 a0 = *(const f32x4*)(Of + base);
  f32x4 a1 = *(const f32x4*)(Of + base + 4);
  f32x4 b0 = *(const f32x4*)(Of + TOKC + base);
  f32x4 b1 = *(const f32x4*)(Of + TOKC + base + 4);
  f32x4 c0 = *(const f32x4*)(Of + 2 * TOKC + base);
  f32x4 c1 = *(const f32x4*)(Of + 2 * TOKC + base + 4);
  bf16x8 o;
#pragma unroll
  for (int j = 0; j < 4; j++) {
    o[j] = (bf16_t)((a0[j] + b0[j] + c0[j]) * inv);
    o[4 + j] = (bf16_t)((a1[j] + b1[j] + c1[j]) * inv);
  }
  *(bf16x8*)(out + base) = o;
}

extern "C" void kernel_launch(void* const* d_in, const int* in_sizes, int n_in,
                              void* d_out, int out_size, void* d_ws, size_t ws_size,
                              hipStream_t stream) {
  (void)out_size; (void)ws_size;
  char* p = (char*)d_ws;
  int* flag = (int*)p;
  float* stats = (float*)(p + 16);
  float* t32 = (float*)(p + 1024);
  bf16_t* conv = (bf16_t*)(p + 1024 + TOKC * 4);

  const int widx[10] = {4, 8, 9, 10, 11, 15, 18, 22, 24, 26};
  const int wK[10] = {512, 512, 512, 512, 512, 512, 512, 512, 2048, 512};
  const int wN[10] = {512, 512, 512, 512, 512, 512, 512, 4096, 512, 512};
  bool is_wt[28] = {};
  for (int i = 0; i < 10; i++) is_wt[widx[i]] = true;

  ConvArgs ca;
  int off = 0;
  int noff[28];
  for (int i = 0; i < 28; i++) {
    ca.src[i] = (i < n_in) ? d_in[i] : nullptr;
    ca.n[i] = (i < n_in && !is_wt[i]) ? in_sizes[i] : 0;
    ca.off[i] = off;
    noff[i] = off;
    int sz = (i < n_in) ? in_sizes[i] : 0;
    off += ((is_wt[i] ? 0 : sz) + 7) & ~7;
  }
  bf16_t* wt = conv + ((off + 7) & ~7);
  TransArgs ta;
  int woff = 0, wtoff[10];
  for (int i = 0; i < 10; i++) {
    ta.src[i] = d_in[widx[i]];
    ta.dst_off[i] = woff;
    wtoff[i] = woff;
    ta.K[i] = wK[i]; ta.N[i] = wN[i];
    woff += wK[i] * wN[i];
  }
  bf16_t* hn  = wt + woff;
  bf16_t* tb  = hn + TOKC;
  bf16_t* xnt = tb + TOKC;
  bf16_t* qb  = xnt + TOKC;
  bf16_t* kbuf = qb + TOKC;
  bf16_t* vtb = kbuf + TOKC;
  float*  Opart = (float*)(vtb + TOKC);          // 3 x TOKC fp32
  float*  lpart = Opart + 3 * TOKC;              // 3 x 4608*8 fp32
  bf16_t* ub2 = xnt;   // [4608,2048] spans xnt..vtb (all dead by ff1)
  bf16_t* ob  = xnt;

  const bf16_t* xb    = conv + noff[0];
  const bf16_t* ctxb  = conv + noff[1];
  const bf16_t* gn_g  = conv + noff[2];
  const bf16_t* gn_b  = conv + noff[3];
  const bf16_t* b_in  = conv + noff[5];
  const bf16_t* ln1_g = conv + noff[6];
  const bf16_t* ln1_b = conv + noff[7];
  const bf16_t* bo1   = conv + noff[12];
  const bf16_t* ln2_g = conv + noff[13];
  const bf16_t* ln2_b = conv + noff[14];
  const bf16_t* wk2   = conv + noff[16];
  const bf16_t* wv2   = conv + noff[17];
  const bf16_t* bo2   = conv + noff[19];
  const bf16_t* ln3_g = conv + noff[20];
  const bf16_t* ln3_b = conv + noff[21];
  const bf16_t* b_ff1 = conv + noff[23];
  const bf16_t* b_ff2 = conv + noff[25];
  const bf16_t* b_out = conv + noff[27];
  const bf16_t* wt_in  = wt + wtoff[0];
  const bf16_t* wt_q1  = wt + wtoff[1];
  const bf16_t* wt_k1  = wt + wtoff[2];
  const bf16_t* wt_v1  = wt + wtoff[3];
  const bf16_t* wt_o1  = wt + wtoff[4];
  const bf16_t* wt_q2  = wt + wtoff[5];
  const bf16_t* wt_o2  = wt + wtoff[6];
  const bf16_t* wt_ff1 = wt + wtoff[7];
  const bf16_t* wt_ff2 = wt + wtoff[8];
  const bf16_t* wt_out = wt + wtoff[9];

  probe_kernel<<<1, 64, 0, stream>>>(d_in[0], flag);
  convert_kernel<<<dim3(128, 28), 256, 0, stream>>>(ca, flag, conv);
  transpose_kernel<<<dim3(512, 10), 256, 0, stream>>>(ta, flag, wt);

  // GroupNorm + proj_in
  gn_stats_kernel<<<64, 256, 0, stream>>>(xb, stats);
  gn_apply_kernel<<<dim3(36, 8, 2), 256, 0, stream>>>(xb, stats, gn_g, gn_b, xnt);
  gemm64d_kernel<0, 1><<<dim3(8, 72), 256, 0, stream>>>(xnt, 512, wt_in, 512, 512, b_in, 1.f, t32, tb, nullptr, nullptr, nullptr, nullptr);
  // self-attention (K-split flash + reduce)
  ln_kernel<<<1152, 256, 0, stream>>>(t32, ln1_g, ln1_b, hn);
  qkv3_kernel<<<dim3(8, 72), 256, 0, stream>>>(hn, wt_q1, wt_k1, wt_v1, qb, kbuf, vtb);
  flash7_kernel<3, false><<<dim3(36, 16, 3), 256, 0, stream>>>(qb, kbuf, vtb, ob, Opart, lpart, 2304, 2304 * 512, 2304);
  att_reduce_kernel<<<1152, 256, 0, stream>>>(Opart, lpart, ob);
  gemm64d_kernel<0, 2><<<dim3(8, 72), 256, 0, stream>>>(ob, 512, wt_o1, 512, 512, bo1, 1.f, t32, tb, nullptr, nullptr, nullptr, nullptr);
  // cross-attention
  ln_kernel<<<1152, 256, 0, stream>>>(t32, ln2_g, ln2_b, hn);
  gemm64d_kernel<0, 0><<<dim3(8, 72), 256, 0, stream>>>(hn, 512, wt_q2, 512, 512, nullptr, QK_SCALE, nullptr, qb, nullptr, nullptr, nullptr, nullptr);
  kv2_kernel<<<dim3(8, 3, 2), 256, 0, stream>>>(ctxb, wk2, wv2, kbuf, vtb);
  flash7_kernel<1, true><<<dim3(36, 16, 1), 256, 0, stream>>>(qb, kbuf, vtb, ob, nullptr, nullptr, 77, 77 * 512, 128);
  gemm64d_kernel<0, 2><<<dim3(8, 72), 256, 0, stream>>>(ob, 512, wt_o2, 512, 512, bo2, 1.f, t32, tb, nullptr, nullptr, nullptr, nullptr);
  // GEGLU feed-forward
  ln_kernel<<<1152, 256, 0, stream>>>(t32, ln3_g, ln3_b, hn);
  ff1_kernel<<<dim3(32, 72), 256, 0, stream>>>(hn, wt_ff1, b_ff1, ub2);
  gemm64d_kernel<0, 2><<<dim3(8, 72), 256, 0, stream>>>(ub2, 2048, wt_ff2, 2048, 512, b_ff2, 1.f, t32, tb, nullptr, nullptr, nullptr, nullptr);
  // proj_out: dtype-adaptive output + residual
  gemm64d_kernel<1, 3><<<dim3(8, 72), 256, 0, stream>>>(tb, 512, wt_out, 512, 512, b_out, 1.f, nullptr, (bf16_t*)d_out, xb, (const float*)d_in[0], (float*)d_out, flag);
}